// Round 2
// baseline (1081.968 us; speedup 1.0000x reference)
//
#include <hip/hip_runtime.h>
#include <math.h>

#define EPSV 1e-8f

// ---------------------------------------------------------------------------
// K1: per-edge weight + degree/count histograms
// ---------------------------------------------------------------------------
__global__ void edge_weights_kernel(const float* __restrict__ logit,
                                    const int* __restrict__ cu,
                                    const int* __restrict__ ci,
                                    float* __restrict__ deg_u,
                                    float* __restrict__ deg_i,
                                    int* __restrict__ cnt_u,
                                    int* __restrict__ cnt_i,
                                    int E) {
    int e = blockIdx.x * blockDim.x + threadIdx.x;
    if (e >= E) return;
    float x = logit[e];
    // stable softplus: log1p(exp(x)) = max(x,0) + log1p(exp(-|x|))
    float w = fmaxf(x, 0.f) + log1pf(expf(-fabsf(x))) + EPSV;
    int u = cu[e], i = ci[e];
    atomicAdd(deg_u + u, w);
    atomicAdd(deg_i + i, w);
    atomicAdd(cnt_u + u, 1);
    atomicAdd(cnt_i + i, 1);
}

// ---------------------------------------------------------------------------
// K2: exclusive prefix scan of both count arrays (block 0: users, block 1: items)
// 1024 threads = 16 waves; wave shuffle scan + LDS wave-sum scan.
// ---------------------------------------------------------------------------
__device__ inline int wave_incl_scan(int v, int lane) {
    #pragma unroll
    for (int off = 1; off < 64; off <<= 1) {
        int t = __shfl_up(v, off, 64);
        if (lane >= off) v += t;
    }
    return v;
}

__global__ void scan2_kernel(const int* __restrict__ cnt_u, int* __restrict__ rs_u, int nu,
                             const int* __restrict__ cnt_i, int* __restrict__ rs_i, int ni) {
    const int* cnt = (blockIdx.x == 0) ? cnt_u : cnt_i;
    int* rs        = (blockIdx.x == 0) ? rs_u  : rs_i;
    int n          = (blockIdx.x == 0) ? nu    : ni;

    __shared__ int wsum[16];
    __shared__ int running;
    int lane = threadIdx.x & 63;
    int wid  = threadIdx.x >> 6;
    if (threadIdx.x == 0) running = 0;
    __syncthreads();

    for (int base = 0; base < n; base += 1024) {
        int idx = base + threadIdx.x;
        int v = (idx < n) ? cnt[idx] : 0;
        int incl = wave_incl_scan(v, lane);
        if (lane == 63) wsum[wid] = incl;
        __syncthreads();
        if (wid == 0 && lane < 16) {
            int s = wsum[lane];
            #pragma unroll
            for (int off = 1; off < 16; off <<= 1) {
                int t = __shfl_up(s, off, 64);
                if (lane >= off) s += t;
            }
            wsum[lane] = s;  // inclusive scan of wave sums
        }
        __syncthreads();
        int wave_excl = (wid == 0) ? 0 : wsum[wid - 1];
        int total     = wsum[15];
        int r         = running;
        if (idx < n) rs[idx] = r + wave_excl + incl - v;
        __syncthreads();
        if (threadIdx.x == 0) running += total;
        __syncthreads();
    }
}

// ---------------------------------------------------------------------------
// K3: fill CSR (users) and CSC (items) with packed (neighbor, norm) pairs
// ---------------------------------------------------------------------------
__global__ void edge_fill_kernel(const float* __restrict__ logit,
                                 const int* __restrict__ cu,
                                 const int* __restrict__ ci,
                                 const float* __restrict__ deg_u,
                                 const float* __restrict__ deg_i,
                                 const int* __restrict__ rs_u,
                                 const int* __restrict__ rs_i,
                                 int* __restrict__ cur_u,
                                 int* __restrict__ cur_i,
                                 int2* __restrict__ adj_u,
                                 int2* __restrict__ adj_i,
                                 int E) {
    int e = blockIdx.x * blockDim.x + threadIdx.x;
    if (e >= E) return;
    float x = logit[e];
    float w = fmaxf(x, 0.f) + log1pf(expf(-fabsf(x))) + EPSV;
    int u = cu[e], i = ci[e];
    float norm = w * rsqrtf(deg_u[u] + EPSV) * rsqrtf(deg_i[i] + EPSV);
    int wbits = __float_as_int(norm);
    int pu = atomicAdd(cur_u + u, 1);
    adj_u[rs_u[u] + pu] = make_int2(i, wbits);
    int pi = atomicAdd(cur_i + i, 1);
    adj_i[rs_i[i] + pi] = make_int2(u, wbits);
}

// ---------------------------------------------------------------------------
// K4: init features (w + delta) into layer-0 buffers and the output accumulator
// ---------------------------------------------------------------------------
__global__ void init_kernel(const float* __restrict__ user_w, const float* __restrict__ user_d,
                            const float* __restrict__ item_w, const float* __restrict__ item_d,
                            float* __restrict__ U0, float* __restrict__ I0,
                            float* __restrict__ out, int nu64, int total) {
    int idx = blockIdx.x * blockDim.x + threadIdx.x;
    if (idx >= total) return;
    float v;
    if (idx < nu64) {
        v = user_w[idx] + user_d[idx];
        U0[idx] = v;
    } else {
        int j = idx - nu64;
        v = item_w[j] + item_d[j];
        I0[j] = v;
    }
    out[idx] = v;
}

// ---------------------------------------------------------------------------
// K5: gather SpMM — one wave per output row, lane = feature dim
// ---------------------------------------------------------------------------
__global__ void __launch_bounds__(256)
gather_kernel(const int2* __restrict__ adj,
              const int* __restrict__ rs,
              const int* __restrict__ cnt,
              const float* __restrict__ src,
              float* __restrict__ dst,
              float* __restrict__ acc,
              int nrows, int is_final) {
    int row  = blockIdx.x * (blockDim.x >> 6) + (threadIdx.x >> 6);
    int lane = threadIdx.x & 63;
    if (row >= nrows) return;

    int k   = rs[row];
    int end = k + cnt[row];
    float a = 0.f;

    for (; k + 3 < end; k += 4) {
        int2 p0 = adj[k];
        int2 p1 = adj[k + 1];
        int2 p2 = adj[k + 2];
        int2 p3 = adj[k + 3];
        float s0 = src[p0.x * 64 + lane];
        float s1 = src[p1.x * 64 + lane];
        float s2 = src[p2.x * 64 + lane];
        float s3 = src[p3.x * 64 + lane];
        a += __int_as_float(p0.y) * s0;
        a += __int_as_float(p1.y) * s1;
        a += __int_as_float(p2.y) * s2;
        a += __int_as_float(p3.y) * s3;
    }
    for (; k < end; ++k) {
        int2 p = adj[k];
        a += __int_as_float(p.y) * src[p.x * 64 + lane];
    }

    int o = row * 64 + lane;
    if (is_final) {
        acc[o] = (acc[o] + a) * 0.25f;   // scale = 1/(NUM_LAYERS+1)
    } else {
        dst[o] = a;
        acc[o] += a;
    }
}

// ---------------------------------------------------------------------------
extern "C" void kernel_launch(void* const* d_in, const int* in_sizes, int n_in,
                              void* d_out, int out_size, void* d_ws, size_t ws_size,
                              hipStream_t stream) {
    const float* user_w = (const float*)d_in[0];
    const float* item_w = (const float*)d_in[1];
    const float* user_d = (const float*)d_in[2];
    const float* item_d = (const float*)d_in[3];
    const float* logit  = (const float*)d_in[4];
    const int*   cu     = (const int*)d_in[5];
    const int*   ci     = (const int*)d_in[6];

    const int NU = in_sizes[0] / 64;
    const int NI = in_sizes[1] / 64;
    const int E  = in_sizes[4];

    // ---- workspace carve-up (256 B aligned) ----
    char* ws = (char*)d_ws;
    size_t off = 0;
    auto carve = [&](size_t bytes) -> void* {
        void* p = ws + off;
        off = (off + bytes + 255) & ~(size_t)255;
        return p;
    };
    // zero-initialized region (one memset covers all six):
    float* deg_u = (float*)carve((size_t)NU * 4);
    float* deg_i = (float*)carve((size_t)NI * 4);
    int*   cnt_u = (int*)carve((size_t)NU * 4);
    int*   cnt_i = (int*)carve((size_t)NI * 4);
    int*   cur_u = (int*)carve((size_t)NU * 4);
    int*   cur_i = (int*)carve((size_t)NI * 4);
    size_t zero_bytes = off;
    // rest:
    int*  rs_u  = (int*)carve((size_t)NU * 4);
    int*  rs_i  = (int*)carve((size_t)NI * 4);
    int2* adj_u = (int2*)carve((size_t)E * 8);
    int2* adj_i = (int2*)carve((size_t)E * 8);
    float* U0 = (float*)carve((size_t)NU * 64 * 4);
    float* U1 = (float*)carve((size_t)NU * 64 * 4);
    float* I0 = (float*)carve((size_t)NI * 64 * 4);
    float* I1 = (float*)carve((size_t)NI * 64 * 4);
    (void)ws_size;

    float* out_u = (float*)d_out;
    float* out_i = out_u + (size_t)NU * 64;

    hipMemsetAsync(d_ws, 0, zero_bytes, stream);

    // build phase
    {
        int blocks = (E + 255) / 256;
        edge_weights_kernel<<<blocks, 256, 0, stream>>>(logit, cu, ci, deg_u, deg_i,
                                                        cnt_u, cnt_i, E);
        scan2_kernel<<<2, 1024, 0, stream>>>(cnt_u, rs_u, NU, cnt_i, rs_i, NI);
        edge_fill_kernel<<<blocks, 256, 0, stream>>>(logit, cu, ci, deg_u, deg_i,
                                                     rs_u, rs_i, cur_u, cur_i,
                                                     adj_u, adj_i, E);
    }

    // init features + accumulator
    {
        int total = (NU + NI) * 64;
        int blocks = (total + 255) / 256;
        init_kernel<<<blocks, 256, 0, stream>>>(user_w, user_d, item_w, item_d,
                                                U0, I0, (float*)d_out, NU * 64, total);
    }

    // 3 propagation layers (gather both directions from the OLD buffers)
    float* Ucur = U0; float* Unew = U1;
    float* Icur = I0; float* Inew = I1;
    const int NUM_LAYERS = 3;
    for (int l = 0; l < NUM_LAYERS; ++l) {
        int fin = (l == NUM_LAYERS - 1) ? 1 : 0;
        int gu = (NU + 3) / 4;  // 4 waves (rows) per 256-thread block
        int gi = (NI + 3) / 4;
        gather_kernel<<<gu, 256, 0, stream>>>(adj_u, rs_u, cnt_u, Icur, Unew, out_u, NU, fin);
        gather_kernel<<<gi, 256, 0, stream>>>(adj_i, rs_i, cnt_i, Ucur, Inew, out_i, NI, fin);
        float* t;
        t = Ucur; Ucur = Unew; Unew = t;
        t = Icur; Icur = Inew; Inew = t;
    }
}

// Round 4
// 784.118 us; speedup vs baseline: 1.3799x; 1.3799x over previous
//
#include <hip/hip_runtime.h>
#include <math.h>

#define EPSV 1e-8f

constexpr int SCAN_BLK  = 1024;
constexpr int SCAN_VPT  = 4;
constexpr int SCAN_TILE = SCAN_BLK * SCAN_VPT;   // 4096

// ---------------------------------------------------------------------------
// K1: per-edge count histogram; records each edge's slot within its row.
// Only 2 atomics per edge (was 4). pos arrays kill the cursor atomics in fill.
// ---------------------------------------------------------------------------
__global__ void count_pos_kernel(const int* __restrict__ cu,
                                 const int* __restrict__ ci,
                                 int* __restrict__ cnt,      // [NU+NI], zeroed
                                 int* __restrict__ pos_u,    // [E]
                                 int* __restrict__ pos_i,    // [E]
                                 int NU, int E) {
    int e = blockIdx.x * blockDim.x + threadIdx.x;
    if (e >= E) return;
    pos_u[e] = atomicAdd(&cnt[cu[e]], 1);
    pos_i[e] = atomicAdd(&cnt[NU + ci[e]], 1);
}

// ---------------------------------------------------------------------------
// Scan phase: 3-kernel parallel exclusive scan of cnt[N] -> rs[N]
// ---------------------------------------------------------------------------
__device__ inline int wave_incl_scan(int v, int lane) {
    #pragma unroll
    for (int off = 1; off < 64; off <<= 1) {
        int t = __shfl_up(v, off, 64);
        if (lane >= off) v += t;
    }
    return v;
}

__global__ void tile_sum_kernel(const int* __restrict__ cnt,
                                int* __restrict__ tsum, int N) {
    __shared__ int ws[16];
    int base = blockIdx.x * SCAN_TILE + threadIdx.x * SCAN_VPT;
    int s = 0;
    if (base + 3 < N) {
        int4 q = *(const int4*)(cnt + base);
        s = q.x + q.y + q.z + q.w;
    } else {
        for (int j = 0; j < SCAN_VPT; ++j) if (base + j < N) s += cnt[base + j];
    }
    #pragma unroll
    for (int off = 1; off < 64; off <<= 1) s += __shfl_xor(s, off, 64);
    int lane = threadIdx.x & 63, wid = threadIdx.x >> 6;
    if (lane == 0) ws[wid] = s;
    __syncthreads();
    if (threadIdx.x < 16) {
        int t = ws[threadIdx.x];
        #pragma unroll
        for (int off = 1; off < 16; off <<= 1) t += __shfl_xor(t, off, 64);
        if (threadIdx.x == 0) tsum[blockIdx.x] = t;
    }
}

// single wave scans tile totals in place -> exclusive tile offsets (NT <= 64)
__global__ void scan_tsum_kernel(int* __restrict__ tsum, int NT) {
    int lane = threadIdx.x;
    int v = (lane < NT) ? tsum[lane] : 0;
    int incl = wave_incl_scan(v, lane);
    if (lane < NT) tsum[lane] = incl - v;
}

__global__ void scan_tile_kernel(const int* __restrict__ cnt,
                                 const int* __restrict__ tsum,
                                 int* __restrict__ rs, int N) {
    __shared__ int ws[16];
    int lane = threadIdx.x & 63, wid = threadIdx.x >> 6;
    int base = blockIdx.x * SCAN_TILE + threadIdx.x * SCAN_VPT;
    int v0 = 0, v1 = 0, v2 = 0, v3 = 0;
    if (base + 3 < N) {
        int4 q = *(const int4*)(cnt + base);
        v0 = q.x; v1 = q.y; v2 = q.z; v3 = q.w;
    } else {
        if (base + 0 < N) v0 = cnt[base + 0];
        if (base + 1 < N) v1 = cnt[base + 1];
        if (base + 2 < N) v2 = cnt[base + 2];
        if (base + 3 < N) v3 = cnt[base + 3];
    }
    int tot = v0 + v1 + v2 + v3;
    int incl = wave_incl_scan(tot, lane);
    if (lane == 63) ws[wid] = incl;
    __syncthreads();
    if (threadIdx.x < 16) {
        int t = ws[threadIdx.x];
        #pragma unroll
        for (int off = 1; off < 16; off <<= 1) {
            int u = __shfl_up(t, off, 64);
            if ((int)threadIdx.x >= off) t += u;
        }
        ws[threadIdx.x] = t;
    }
    __syncthreads();
    int wexcl = (wid == 0) ? 0 : ws[wid - 1];
    int excl = tsum[blockIdx.x] + wexcl + (incl - tot);
    int r0 = excl, r1 = r0 + v0, r2 = r1 + v1, r3 = r2 + v2;
    if (base + 3 < N) {
        *(int4*)(rs + base) = make_int4(r0, r1, r2, r3);
    } else {
        if (base + 0 < N) rs[base + 0] = r0;
        if (base + 1 < N) rs[base + 1] = r1;
        if (base + 2 < N) rs[base + 2] = r2;
        if (base + 3 < N) rs[base + 3] = r3;
    }
}

// ---------------------------------------------------------------------------
// K3: fill unified adjacency. Entry = (global neighbor row id, raw weight w).
// No atomics: slot = rs[row] + pos[e].
// ---------------------------------------------------------------------------
__global__ void fill_kernel(const float* __restrict__ logit,
                            const int* __restrict__ cu,
                            const int* __restrict__ ci,
                            const int* __restrict__ rs,
                            const int* __restrict__ pos_u,
                            const int* __restrict__ pos_i,
                            int2* __restrict__ adj,
                            int NU, int E) {
    int e = blockIdx.x * blockDim.x + threadIdx.x;
    if (e >= E) return;
    float x = logit[e];
    float w = fmaxf(x, 0.f) + log1pf(expf(-fabsf(x))) + EPSV;  // stable softplus
    int wb = __float_as_int(w);
    int u = cu[e];
    int gi = NU + ci[e];
    adj[rs[u]  + pos_u[e]] = make_int2(gi, wb);
    adj[rs[gi] + pos_i[e]] = make_int2(u,  wb);
}

// ---------------------------------------------------------------------------
// K4: per-row degree -> rsqrt(deg+eps). Wave per row, coalesced entry reads.
// ---------------------------------------------------------------------------
__global__ void deg_kernel(const int2* __restrict__ adj,
                           const int* __restrict__ rs,
                           const int* __restrict__ cnt,
                           float* __restrict__ rsq, int N) {
    int row  = blockIdx.x * (blockDim.x >> 6) + (threadIdx.x >> 6);
    int lane = threadIdx.x & 63;
    if (row >= N) return;
    int b = rs[row], n = cnt[row];
    float s = 0.f;
    for (int j = lane; j < n; j += 64) s += __int_as_float(adj[b + j].y);
    #pragma unroll
    for (int off = 1; off < 64; off <<= 1) s += __shfl_xor(s, off, 64);
    if (lane == 0) rsq[row] = rsqrtf(s + EPSV);
}

// ---------------------------------------------------------------------------
// K5: scale adjacency values to final norm = w * rsq[row] * rsq[nbr]
// ---------------------------------------------------------------------------
__global__ void scale_kernel(int2* __restrict__ adj,
                             const int* __restrict__ rs,
                             const int* __restrict__ cnt,
                             const float* __restrict__ rsq, int N) {
    int row  = blockIdx.x * (blockDim.x >> 6) + (threadIdx.x >> 6);
    int lane = threadIdx.x & 63;
    if (row >= N) return;
    float rr = rsq[row];
    int b = rs[row], n = cnt[row];
    for (int j = lane; j < n; j += 64) {
        int2 v = adj[b + j];
        v.y = __float_as_int(__int_as_float(v.y) * rr * rsq[v.x]);
        adj[b + j] = v;
    }
}

// ---------------------------------------------------------------------------
// K6: init fused feature buffer F0 (= w + delta) and output accumulator
// ---------------------------------------------------------------------------
__global__ void init_kernel(const float* __restrict__ user_w, const float* __restrict__ user_d,
                            const float* __restrict__ item_w, const float* __restrict__ item_d,
                            float* __restrict__ F0, float* __restrict__ out,
                            int nu64, int total) {
    int idx = blockIdx.x * blockDim.x + threadIdx.x;
    if (idx >= total) return;
    float v;
    if (idx < nu64) {
        v = user_w[idx] + user_d[idx];
    } else {
        int j = idx - nu64;
        v = item_w[j] + item_d[j];
    }
    F0[idx] = v;
    out[idx] = v;
}

// ---------------------------------------------------------------------------
// K7: fused gather SpMM over all 150k rows (both directions in one launch).
// One wave per row, lane = feature dim. 8-deep unroll for MLP.
// ---------------------------------------------------------------------------
__global__ void __launch_bounds__(256)
gather_kernel(const int2* __restrict__ adj,
              const int* __restrict__ rs,
              const int* __restrict__ cnt,
              const float* __restrict__ src,
              float* __restrict__ dst,
              float* __restrict__ acc,
              int N, int is_final) {
    int row  = blockIdx.x * (blockDim.x >> 6) + (threadIdx.x >> 6);
    int lane = threadIdx.x & 63;
    if (row >= N) return;

    int k   = rs[row];
    int end = k + cnt[row];
    float a = 0.f;

    for (; k + 7 < end; k += 8) {
        int2 p0 = adj[k];     int2 p1 = adj[k + 1];
        int2 p2 = adj[k + 2]; int2 p3 = adj[k + 3];
        int2 p4 = adj[k + 4]; int2 p5 = adj[k + 5];
        int2 p6 = adj[k + 6]; int2 p7 = adj[k + 7];
        float s0 = src[(size_t)p0.x * 64 + lane];
        float s1 = src[(size_t)p1.x * 64 + lane];
        float s2 = src[(size_t)p2.x * 64 + lane];
        float s3 = src[(size_t)p3.x * 64 + lane];
        float s4 = src[(size_t)p4.x * 64 + lane];
        float s5 = src[(size_t)p5.x * 64 + lane];
        float s6 = src[(size_t)p6.x * 64 + lane];
        float s7 = src[(size_t)p7.x * 64 + lane];
        a += __int_as_float(p0.y) * s0;
        a += __int_as_float(p1.y) * s1;
        a += __int_as_float(p2.y) * s2;
        a += __int_as_float(p3.y) * s3;
        a += __int_as_float(p4.y) * s4;
        a += __int_as_float(p5.y) * s5;
        a += __int_as_float(p6.y) * s6;
        a += __int_as_float(p7.y) * s7;
    }
    for (; k + 3 < end; k += 4) {
        int2 p0 = adj[k];     int2 p1 = adj[k + 1];
        int2 p2 = adj[k + 2]; int2 p3 = adj[k + 3];
        float s0 = src[(size_t)p0.x * 64 + lane];
        float s1 = src[(size_t)p1.x * 64 + lane];
        float s2 = src[(size_t)p2.x * 64 + lane];
        float s3 = src[(size_t)p3.x * 64 + lane];
        a += __int_as_float(p0.y) * s0;
        a += __int_as_float(p1.y) * s1;
        a += __int_as_float(p2.y) * s2;
        a += __int_as_float(p3.y) * s3;
    }
    for (; k < end; ++k) {
        int2 p = adj[k];
        a += __int_as_float(p.y) * src[(size_t)p.x * 64 + lane];
    }

    size_t o = (size_t)row * 64 + lane;
    if (is_final) {
        acc[o] = (acc[o] + a) * 0.25f;   // scale = 1/(NUM_LAYERS+1)
    } else {
        dst[o] = a;
        acc[o] += a;
    }
}

// ---------------------------------------------------------------------------
extern "C" void kernel_launch(void* const* d_in, const int* in_sizes, int n_in,
                              void* d_out, int out_size, void* d_ws, size_t ws_size,
                              hipStream_t stream) {
    const float* user_w = (const float*)d_in[0];
    const float* item_w = (const float*)d_in[1];
    const float* user_d = (const float*)d_in[2];
    const float* item_d = (const float*)d_in[3];
    const float* logit  = (const float*)d_in[4];
    const int*   cu     = (const int*)d_in[5];
    const int*   ci     = (const int*)d_in[6];

    const int NU = in_sizes[0] / 64;
    const int NI = in_sizes[1] / 64;
    const int E  = in_sizes[4];
    const int N  = NU + NI;                    // unified row count
    const int NT = (N + SCAN_TILE - 1) / SCAN_TILE;   // scan tiles (37 <= 64)

    // ---- workspace carve-up (256 B aligned); cnt FIRST (single memset) ----
    char* ws = (char*)d_ws;
    size_t off = 0;
    auto carve = [&](size_t bytes) -> void* {
        void* p = ws + off;
        off = (off + bytes + 255) & ~(size_t)255;
        return p;
    };
    int*   cnt   = (int*)carve((size_t)N * 4);       // zeroed each call
    size_t zero_bytes = off;
    int*   rs    = (int*)carve((size_t)N * 4);
    float* rsq   = (float*)carve((size_t)N * 4);
    int*   tsum  = (int*)carve((size_t)128 * 4);
    int*   pos_u = (int*)carve((size_t)E * 4);
    int*   pos_i = (int*)carve((size_t)E * 4);
    int2*  adj   = (int2*)carve((size_t)2 * E * 8);
    float* F0    = (float*)carve((size_t)N * 64 * 4);
    float* F1    = (float*)carve((size_t)N * 64 * 4);
    (void)ws_size;

    float* out = (float*)d_out;

    hipMemsetAsync(cnt, 0, zero_bytes, stream);

    // ---- build phase ----
    {
        int eblocks = (E + 255) / 256;
        count_pos_kernel<<<eblocks, 256, 0, stream>>>(cu, ci, cnt, pos_u, pos_i, NU, E);
        tile_sum_kernel<<<NT, SCAN_BLK, 0, stream>>>(cnt, tsum, N);
        scan_tsum_kernel<<<1, 64, 0, stream>>>(tsum, NT);
        scan_tile_kernel<<<NT, SCAN_BLK, 0, stream>>>(cnt, tsum, rs, N);
        fill_kernel<<<eblocks, 256, 0, stream>>>(logit, cu, ci, rs, pos_u, pos_i,
                                                 adj, NU, E);
        int rblocks = (N + 3) / 4;
        deg_kernel<<<rblocks, 256, 0, stream>>>(adj, rs, cnt, rsq, N);
        scale_kernel<<<rblocks, 256, 0, stream>>>(adj, rs, cnt, rsq, N);
    }

    // ---- init features + accumulator ----
    {
        int total = N * 64;
        init_kernel<<<(total + 255) / 256, 256, 0, stream>>>(user_w, user_d,
                                                             item_w, item_d,
                                                             F0, out, NU * 64, total);
    }

    // ---- 3 propagation layers, both directions fused per launch ----
    float* Fc = F0; float* Fn = F1;
    const int NUM_LAYERS = 3;
    int rblocks = (N + 3) / 4;
    for (int l = 0; l < NUM_LAYERS; ++l) {
        int fin = (l == NUM_LAYERS - 1) ? 1 : 0;
        gather_kernel<<<rblocks, 256, 0, stream>>>(adj, rs, cnt, Fc, Fn, out, N, fin);
        float* t = Fc; Fc = Fn; Fn = t;
    }
}